// Round 11
// baseline (172.558 us; speedup 1.0000x reference)
//
#include <hip/hip_runtime.h>
#include <hip/hip_fp16.h>

#define Bn  4
#define Hn  256
#define Wn  256
#define Cn  16
#define NTn 9
#define HWn (Hn*Wn)
#define KF  129      // W/2 + 1
#define KGP 136      // padded k-row length of G
#define SRL 256      // scratch row length (R11: was 266; row-XOR swizzle replaces pad)
#define PI_F 3.14159265358979323846f

// R11 swizzle: column bank-pair map (i ^ (i>>2)) & 15 (R8, bijective on every
// 16-index subspace the FFT phases use) XOR'd with the GLOBAL ROW index.
// The row-XOR replaces SRL-padding row-stagger: with SRL=256 rows are
// bank-aligned, but the store phase's 4-row groups get XOR {r, r^4, r^8, r^12}
// -> 4 distinct bank-pairs -> conflict-free (kills the residual 1.92M 2-way
// conflicts as well). Exchange phases see a per-instruction-constant XOR ->
// bijection preserved. Pure layout change; numerics bit-identical.
__device__ __forceinline__ int swz2(int row, int i) {
  return (i & ~15) | (((i ^ (i >> 2)) ^ row) & 15);
}

// Natural position of final-radix4 register a: X[dr(lane) + 64a].
__device__ __forceinline__ int drof(int lane) {
  return ((lane & 3) << 4) + (((lane >> 2) & 3) << 2) + (lane >> 4);
}

// Vector-form complex multiply: lowers to v_pk_mul_f32 + v_pk_fma_f32.
__device__ __forceinline__ float2 cmul(float2 a, float2 b) {
  float2 r = make_float2(a.x, a.x) * b;
  return r + make_float2(-a.y, a.y) * make_float2(b.y, b.x);
}

// Vector-form radix-4 butterfly: packed f32 adds (v_pk_add_f32).
template<bool INV>
__device__ __forceinline__ void radix4(float2& x0, float2& x1, float2& x2, float2& x3) {
  float2 y0 = x0 + x2;
  float2 y1 = x0 - x2;
  float2 y2 = x1 + x3;
  float2 y3 = x1 - x3;
  float2 j3 = INV ? make_float2(-y3.y, y3.x) : make_float2(y3.y, -y3.x);
  x0 = y0 + y2;
  x2 = y0 - y2;
  x1 = y1 + j3;   // fwd: y1 - i*y3 ; inv: y1 + i*y3
  x3 = y1 - j3;
}

struct Tw { float2 a1,a2,a3,b1,b2,b3,c1,c2,c3; };

template<bool INV>
__device__ __forceinline__ Tw make_tw(int lane) {
  const float sgn = INV ? 2.0f * PI_F : -2.0f * PI_F;
  Tw t; float sw, cw;
  __sincosf(sgn * (float)lane / 256.0f, &sw, &cw);
  t.a1 = make_float2(cw, sw); t.a2 = cmul(t.a1, t.a1); t.a3 = cmul(t.a2, t.a1);
  __sincosf(sgn * (float)(lane & 15) / 64.0f, &sw, &cw);
  t.b1 = make_float2(cw, sw); t.b2 = cmul(t.b1, t.b1); t.b3 = cmul(t.b2, t.b1);
  __sincosf(sgn * (float)(lane & 3) / 16.0f, &sw, &cw);
  t.c1 = make_float2(cw, sw); t.c2 = cmul(t.c1, t.c1); t.c3 = cmul(t.c2, t.c1);
  return t;
}

// ---------------------------------------------------------------------------
// NF per-wave FFT-256s in LOCKSTEP, ENDING IN REGISTERS (R9): after the call,
// v[f][a] = X_f[drof(lane) + 64a]. r0 = GLOBAL row index of s[0] within the
// block's scratch (for the row-XOR swizzle). No explicit lgkmcnt drains (R5):
// DS ops in a wave are in-order; compiler inserts counted waits. Cross-wave
// consumers sit behind __syncthreads() in the callers.
// ---------------------------------------------------------------------------
template<bool INV, int NF>
__device__ __forceinline__ void fft256_reg(float2 (*v)[4], float2 (*s)[SRL],
                                           int lane, const Tw& t, int r0) {
#pragma unroll
  for (int f = 0; f < NF; ++f) {
    radix4<INV>(v[f][0], v[f][1], v[f][2], v[f][3]);
    v[f][1] = cmul(v[f][1], t.a1); v[f][2] = cmul(v[f][2], t.a2); v[f][3] = cmul(v[f][3], t.a3);
#pragma unroll
    for (int a = 0; a < 4; ++a) s[f][swz2(r0 + f, lane + (a << 6))] = v[f][a];
  }
  { int base = (lane >> 4) * 64 + (lane & 15);
#pragma unroll
    for (int f = 0; f < NF; ++f)
#pragma unroll
      for (int a = 0; a < 4; ++a) v[f][a] = s[f][swz2(r0 + f, base + (a << 4))];
  }
#pragma unroll
  for (int f = 0; f < NF; ++f) {
    radix4<INV>(v[f][0], v[f][1], v[f][2], v[f][3]);
    v[f][1] = cmul(v[f][1], t.b1); v[f][2] = cmul(v[f][2], t.b2); v[f][3] = cmul(v[f][3], t.b3);
    int base = (lane >> 4) * 64 + (lane & 15);
#pragma unroll
    for (int a = 0; a < 4; ++a) s[f][swz2(r0 + f, base + (a << 4))] = v[f][a];
  }
  { int base = (lane >> 4) * 64 + ((lane >> 2) & 3) * 16 + (lane & 3);
#pragma unroll
    for (int f = 0; f < NF; ++f)
#pragma unroll
      for (int a = 0; a < 4; ++a) v[f][a] = s[f][swz2(r0 + f, base + (a << 2))];
  }
#pragma unroll
  for (int f = 0; f < NF; ++f) {
    radix4<INV>(v[f][0], v[f][1], v[f][2], v[f][3]);
    v[f][1] = cmul(v[f][1], t.c1); v[f][2] = cmul(v[f][2], t.c2); v[f][3] = cmul(v[f][3], t.c3);
    int base = (lane & ~3) * 4 + (lane & 3);
#pragma unroll
    for (int a = 0; a < 4; ++a) s[f][swz2(r0 + f, base + (a << 2))] = v[f][a];
  }
  { int base = lane * 4;
#pragma unroll
    for (int f = 0; f < NF; ++f)
#pragma unroll
      for (int a = 0; a < 4; ++a) v[f][a] = s[f][swz2(r0 + f, base + a)];
  }
#pragma unroll
  for (int f = 0; f < NF; ++f)
    radix4<INV>(v[f][0], v[f][1], v[f][2], v[f][3]);
}

// Full variant: natural order in s[f][swz2(r0+f, k)].
template<bool INV, int NF>
__device__ __forceinline__ void fft256_n(float2 (*v)[4], float2 (*s)[SRL],
                                         int lane, const Tw& t, int r0) {
  fft256_reg<INV, NF>(v, s, lane, t, r0);
  int dr = drof(lane);
#pragma unroll
  for (int f = 0; f < NF; ++f)
#pragma unroll
    for (int a = 0; a < 4; ++a) s[f][swz2(r0 + f, dr + (a << 6))] = v[f][a];
}

// Inline projective warp map (matches reference: fp-contract off, rintf).
// When 'affine' (wave-uniform), kk == 1.0f exactly for every pixel, so the
// two IEEE divides are skipped bit-exactly.
__device__ __forceinline__ int warp_id2(float a0, float a2, float a3, float a5,
                                        float a6, float p1, float p4, float p7,
                                        bool affine, int col) {
#pragma clang fp contract(off)
  float x = (float)col;
  float xf = (a0 * x + p1) + a2;
  float yf = (a3 * x + p4) + a5;
  if (!affine) {
    float kk = (a6 * x + p7) + 1.0f;
    xf = xf / kk;
    yf = yf / kk;
  }
  float xr = rintf(xf), yr = rintf(yf);
  bool valid = (xr >= 0.f) && (xr < 256.f) && (yr >= 0.f) && (yr < 256.f);
  return valid ? ((int)yr * Wn + (int)xr) : -1;
}

// ---------------------------------------------------------------------------
// Row FFT of warped y (t=0 slab == x spectra). Block = (tb, cg quad, 16-row
// chunk) — NATURAL mapping (R3 XCD-swizzle and R6 cg-fold both regressed).
// Half-1 gather issued BEFORE half-0's store phase. No min-waves bound (R2
// spilled). R11: LDS = sb only = exactly 32 KB -> 5 blocks/CU (was 4); the
// nyacc cross-wave reduction reuses sb after the last store phase.
// ---------------------------------------------------------------------------
__global__ __launch_bounds__(256) void k_yrow(const float* __restrict__ inp,
                                              const float* __restrict__ T,
                                              __half2* __restrict__ Yh,
                                              float* __restrict__ part) {
  __shared__ float2 sb[4][4][SRL];            // 32768 B exactly
  int tid = threadIdx.x, w = tid >> 6, lane = tid & 63;
  Tw t = make_tw<false>(lane);
  int chunk = blockIdx.x & 15, cg = (blockIdx.x >> 4) & 3, tb = blockIdx.x >> 6;
  int b = tb & 3, tt = tb >> 2;
  int i0 = chunk << 4;
  const float4* ib = (const float4*)(inp + (size_t)b * HWn * Cn);
  float a0, a1, a2, a3, a4, a5, a6, a7;
  { const float* a = T + tt * 8;
    a0=a[0]; a1=a[1]; a2=a[2]; a3=a[3]; a4=a[4]; a5=a[5]; a6=a[6]; a7=a[7]; }
  const bool affine = (fabsf(a6) + fabsf(a7)) * 255.0f < 2.9e-8f;
  float4 nyacc = make_float4(0.f, 0.f, 0.f, 0.f);

  // Hermitian-unpack store phase for half h (reads block-wide scratch).
  auto store_half = [&](int h) {
    int ii = tid & 7, kq = tid >> 3;
    int w2 = ii >> 1, odd = ii & 1;
#pragma unroll
    for (int p = 0; p < 5; ++p) {
      int k = p * 32 + kq;
      if (k <= 128) {
        int kc = (256 - k) & 255;
#pragma unroll
        for (int cc = 0; cc < 4; ++cc) {
          int row = w2 * 4 + cc;
          float2 Z  = sb[w2][cc][swz2(row, k)];
          float2 Zc = sb[w2][cc][swz2(row, kc)];
          float2 F = odd ? make_float2(0.5f * (Z.y + Zc.y), 0.5f * (Zc.x - Z.x))
                         : make_float2(0.5f * (Z.x + Zc.x), 0.5f * (Z.y - Zc.y));
          Yh[((size_t)(tb * Cn + cg * 4 + cc) * KF + k) * Hn + i0 + h * 8 + ii] =
              __float22half2_rn(F);
        }
      }
    }
  };

  // ---- half 0: gather + FFT ----
  {
    int r0 = i0 + 2 * w;
    float yA = (float)r0, yB = (float)(r0 + 1);
    float p1A = a1 * yA, p4A = a4 * yA, p7A = a7 * yA;
    float p1B = a1 * yB, p4B = a4 * yB, p7B = a7 * yB;
    float4 g0[4], g1[4];
#pragma unroll
    for (int q = 0; q < 4; ++q) {
      int col = lane + (q << 6);
      int id0 = warp_id2(a0, a2, a3, a5, a6, p1A, p4A, p7A, affine, col);
      int id1 = warp_id2(a0, a2, a3, a5, a6, p1B, p4B, p7B, affine, col);
      g0[q] = (id0 >= 0) ? ib[(size_t)id0 * 4 + cg] : make_float4(0.f,0.f,0.f,0.f);
      g1[q] = (id1 >= 0) ? ib[(size_t)id1 * 4 + cg] : make_float4(0.f,0.f,0.f,0.f);
      nyacc += g0[q] * g0[q] + g1[q] * g1[q];
    }
    float2 v[4][4];
#pragma unroll
    for (int q = 0; q < 4; ++q) {
      v[0][q] = make_float2(g0[q].x, g1[q].x);
      v[1][q] = make_float2(g0[q].y, g1[q].y);
      v[2][q] = make_float2(g0[q].z, g1[q].z);
      v[3][q] = make_float2(g0[q].w, g1[q].w);
    }
    fft256_n<false, 4>(v, sb[w], lane, t, w * 4);
  }
  __syncthreads();

  // ---- issue half-1 gather NOW: latency hides under half-0 store phase ----
  float4 G0[4], G1[4];
  {
    int r1 = i0 + 8 + 2 * w;
    float yA = (float)r1, yB = (float)(r1 + 1);
    float p1A = a1 * yA, p4A = a4 * yA, p7A = a7 * yA;
    float p1B = a1 * yB, p4B = a4 * yB, p7B = a7 * yB;
#pragma unroll
    for (int q = 0; q < 4; ++q) {
      int col = lane + (q << 6);
      int id0 = warp_id2(a0, a2, a3, a5, a6, p1A, p4A, p7A, affine, col);
      int id1 = warp_id2(a0, a2, a3, a5, a6, p1B, p4B, p7B, affine, col);
      G0[q] = (id0 >= 0) ? ib[(size_t)id0 * 4 + cg] : make_float4(0.f,0.f,0.f,0.f);
      G1[q] = (id1 >= 0) ? ib[(size_t)id1 * 4 + cg] : make_float4(0.f,0.f,0.f,0.f);
    }
  }

  store_half(0);
  __syncthreads();

  // ---- half 1: consume prefetched gather + FFT ----
  {
#pragma unroll
    for (int q = 0; q < 4; ++q)
      nyacc += G0[q] * G0[q] + G1[q] * G1[q];
    float2 v[4][4];
#pragma unroll
    for (int q = 0; q < 4; ++q) {
      v[0][q] = make_float2(G0[q].x, G1[q].x);
      v[1][q] = make_float2(G0[q].y, G1[q].y);
      v[2][q] = make_float2(G0[q].z, G1[q].z);
      v[3][q] = make_float2(G0[q].w, G1[q].w);
    }
    fft256_n<false, 4>(v, sb[w], lane, t, w * 4);
  }
  __syncthreads();
  store_half(1);

#pragma unroll
  for (int o = 32; o > 0; o >>= 1) {
    nyacc.x += __shfl_down(nyacc.x, o, 64);
    nyacc.y += __shfl_down(nyacc.y, o, 64);
    nyacc.z += __shfl_down(nyacc.z, o, 64);
    nyacc.w += __shfl_down(nyacc.w, o, 64);
  }
  __syncthreads();                       // all store_half(1) sb reads done
  if (lane == 0) {                        // reuse sb[0][0][0..7] as redw
    sb[0][0][w * 2 + 0] = make_float2(nyacc.x, nyacc.y);
    sb[0][0][w * 2 + 1] = make_float2(nyacc.z, nyacc.w);
  }
  __syncthreads();
  if (tid == 0) {
    float2 sxy = make_float2(0.f, 0.f), szw = make_float2(0.f, 0.f);
#pragma unroll
    for (int ww = 0; ww < 4; ++ww) {
      sxy += sb[0][0][ww * 2 + 0];
      szw += sb[0][0][ww * 2 + 1];
    }
    part[((size_t)tb * Cn + cg * 4 + 0) * 16 + chunk] = sxy.x;
    part[((size_t)tb * Cn + cg * 4 + 1) * 16 + chunk] = sxy.y;
    part[((size_t)tb * Cn + cg * 4 + 2) * 16 + chunk] = szw.x;
    part[((size_t)tb * Cn + cg * 4 + 3) * 16 + chunk] = szw.y;
  }
}

// ---------------------------------------------------------------------------
// Column FFT of x spectra, q4-batched. R9: spectrum stays in registers; the
// output store goes directly to Fxh[dr+64a] — final scratch roundtrip removed.
// ---------------------------------------------------------------------------
__global__ __launch_bounds__(256) void k_colfft_fx(const __half2* __restrict__ Yh,
                                                   __half2* __restrict__ Fxh) {
  __shared__ float2 sb[4][4][SRL];
  int tid = threadIdx.x, w = tid >> 6, lane = tid & 63;
  Tw t = make_tw<false>(lane);
  int base_item = blockIdx.x * 16 + w * 4;   // (b*16+c)*KF + k
  float2 v[4][4];
#pragma unroll
  for (int f = 0; f < 4; ++f) {
    const __half2* Sp = Yh + (size_t)(base_item + f) * Hn;
#pragma unroll
    for (int q = 0; q < 4; ++q) v[f][q] = __half22float2(Sp[lane + (q << 6)]);
  }
  fft256_reg<false, 4>(v, sb[w], lane, t, w * 4);
  int dr = drof(lane);
#pragma unroll
  for (int f = 0; f < 4; ++f) {
    __half2* Op = Fxh + (size_t)(base_item + f) * Hn;
#pragma unroll
    for (int a = 0; a < 4; ++a)
      Op[dr + (a << 6)] = __float22half2_rn(v[f][a]);
  }
}

// ---------------------------------------------------------------------------
// Block = (tb, k-quartet). R9: forward FFTs end in registers; spectral
// product + c-sum runs in PERMUTED order (fx read at dr+64a — coalesced);
// one 8-op scratch roundtrip restores natural order for the inverse FFT.
// t=0 shortcut (R7) kept.
// ---------------------------------------------------------------------------
__global__ __launch_bounds__(256) void k_ycol(const __half2* __restrict__ Yh,
                                              const __half2* __restrict__ Fxh,
                                              const float* __restrict__ part,
                                              float2* __restrict__ G) {
  __shared__ float2 sb[4][4][SRL];
  __shared__ float scs[16];
  int tid = threadIdx.x, w = tid >> 6, lane = tid & 63;
  int tb = blockIdx.x / 33, quart = blockIdx.x % 33;
  int b = tb & 3;
  int k = quart * 4 + w;
  bool act = (k <= 128);
  bool t0 = (tb < 4);                         // tt == 0: identity transform
  const __half2* Ybase = Yh  + ((size_t)(tb * Cn) * KF + k) * Hn;
  const __half2* Fbase = Fxh + ((size_t)(b  * Cn) * KF + k) * Hn;

  float2 va[4][4], vb[4][4];
  auto LOADY = [&](float2 (*v)[4], int c0) {
#pragma unroll
    for (int e = 0; e < 4; ++e) {
      const __half2* Yp = Ybase + (size_t)(c0 + e) * KF * Hn;
#pragma unroll
      for (int q = 0; q < 4; ++q) v[e][q] = __half22float2(Yp[lane + (q << 6)]);
    }
  };
  if (act && !t0) LOADY(va, 0);   // latency hides under scs reduce + barrier

  if (tid < 16) {
    float sx = 0.f, sy = 0.f;
#pragma unroll
    for (int ch = 0; ch < 16; ++ch) {
      sx += part[((size_t)b  * Cn + tid) * 16 + ch];   // t=0 slab == x norms
      sy += part[((size_t)tb * Cn + tid) * 16 + ch];
    }
    scs[tid] = 1.0f / ((float)Cn * (sqrtf(sx) * sqrtf(sy) + 1e-12f));
  }
  __syncthreads();

  if (act) {
    int dr = drof(lane);
    if (!t0) {
      Tw tf = make_tw<false>(lane);
      float2 accp[4];
#pragma unroll
      for (int a = 0; a < 4; ++a) accp[a] = make_float2(0.f, 0.f);
      // fy in regs: vv[e][a] = Fy_e[dr + 64a]; fx read at the same freqs.
      auto ACCP = [&](float2 (*vv)[4], int c0) {
#pragma unroll
        for (int e = 0; e < 4; ++e) {
          float sc = scs[c0 + e];
          const __half2* Fxp = Fbase + (size_t)(c0 + e) * KF * Hn;
#pragma unroll
          for (int a = 0; a < 4; ++a) {
            float2 fy = vv[e][a];
            float2 fx = __half22float2(Fxp[dr + (a << 6)]);
            // fx * conj(fy), packed-f32 form
            float2 pr = make_float2(fy.x, fy.x) * fx
                      + make_float2(fy.y, fy.y) * make_float2(fx.y, -fx.x);
            accp[a] += make_float2(sc, sc) * pr;
          }
        }
      };
      fft256_reg<false, 4>(va, sb[w], lane, tf, w * 4);  LOADY(vb, 4);   ACCP(va, 0);
      fft256_reg<false, 4>(vb, sb[w], lane, tf, w * 4);  LOADY(va, 8);   ACCP(vb, 4);
      fft256_reg<false, 4>(va, sb[w], lane, tf, w * 4);  LOADY(vb, 12);  ACCP(va, 8);
      fft256_reg<false, 4>(vb, sb[w], lane, tf, w * 4);                  ACCP(vb, 12);
      // permuted -> natural roundtrip (wave-private, in-order DS)
#pragma unroll
      for (int a = 0; a < 4; ++a) sb[w][0][swz2(w * 4, dr + (a << 6))] = accp[a];
      float2 v0[1][4];
#pragma unroll
      for (int a = 0; a < 4; ++a) v0[0][a] = sb[w][0][swz2(w * 4, lane + (a << 6))];
      Tw ti = make_tw<true>(lane);
      fft256_n<true, 1>(v0, sb[w], lane, ti, w * 4);
    } else {
      // t=0: corr spectrum = sum_c sc_c * |fx_c|^2 (purely real), natural order
      float2 acc[1][4];
#pragma unroll
      for (int q = 0; q < 4; ++q) acc[0][q] = make_float2(0.f, 0.f);
#pragma unroll
      for (int c = 0; c < Cn; ++c) {
        float sc = scs[c];
        const __half2* Fxp = Fbase + (size_t)c * KF * Hn;
#pragma unroll
        for (int q = 0; q < 4; ++q) {
          float2 fx = __half22float2(Fxp[lane + (q << 6)]);
          acc[0][q].x += sc * (fx.x * fx.x + fx.y * fx.y);
        }
      }
      Tw ti = make_tw<true>(lane);
      fft256_n<true, 1>(acc, sb[w], lane, ti, w * 4);
    }
  }
  __syncthreads();
  // transposed store: 4 consecutive k per j -> 32B granules
  int kk = tid & 3, jj0 = tid >> 2;
  if (quart * 4 + kk <= 128) {
    float2* Gp = G + ((size_t)tb * Hn) * KGP + quart * 4 + kk;
#pragma unroll
    for (int p = 0; p < 4; ++p) {
      int j = jj0 + (p << 6);
      Gp[(size_t)j * KGP] = sb[kk][0][swz2(kk * 4, j)];
    }
  }
}

// ---------------------------------------------------------------------------
// Final pass: block = (b, spatial row i), 5 waves. R9: inverse FFT ends in
// registers; rowbuf written directly at j = dr+64a.
// ---------------------------------------------------------------------------
__global__ __launch_bounds__(320) void k_irow(const float2* __restrict__ G,
                                              float* __restrict__ out) {
  __shared__ float2 tile[5][2][132];
  __shared__ float2 sb[5][SRL];
  __shared__ float rowbuf[Wn * NTn];
  int tid = threadIdx.x, w = tid >> 6, lane = tid & 63;
  Tw ti = make_tw<true>(lane);
  int b = blockIdx.x >> 8, i = blockIdx.x & 255;
  const float scale = 1.0f / ((float)Hn * (float)Wn);
  int t1 = 2 * w, t2 = t1 + 1;
  {
    const float2* Gp1 = G + ((size_t)(t1 * Bn + b) * Hn + i) * KGP;
    for (int k = lane; k < KF; k += 64) tile[w][0][k] = Gp1[k];
    if (t2 < NTn) {
      const float2* Gp2 = G + ((size_t)(t2 * Bn + b) * Hn + i) * KGP;
      for (int k = lane; k < KF; k += 64) tile[w][1][k] = Gp2[k];
    }
  }
  // tile[w] is wave-private; DS in-order + compiler waits handle the reads.
  float2 v[1][4];
#pragma unroll
  for (int q = 0; q < 4; ++q) {
    int k = lane + (q << 6);
    float2 a, bb;
    if (k <= 128) a = tile[w][0][k];
    else { float2 z = tile[w][0][256 - k]; a = make_float2(z.x, -z.y); }
    if (t2 < NTn) {
      if (k <= 128) bb = tile[w][1][k];
      else { float2 z = tile[w][1][256 - k]; bb = make_float2(z.x, -z.y); }
    } else bb = make_float2(0.f, 0.f);
    v[0][q] = a + make_float2(-bb.y, bb.x);   // A + i*B, packed add
  }
  fft256_reg<true, 1>(v, reinterpret_cast<float2(*)[SRL]>(sb[w]), lane, ti, w);
  int dr = drof(lane);
#pragma unroll
  for (int a = 0; a < 4; ++a) {
    int j = dr + (a << 6);
    rowbuf[j * NTn + t1] = v[0][a].x * scale;
    if (t2 < NTn) rowbuf[j * NTn + t2] = v[0][a].y * scale;
  }
  __syncthreads();
  float* ob = out + ((size_t)(b * Hn + i) * Wn) * NTn;
  for (int f = tid; f < Wn * NTn; f += 320) ob[f] = rowbuf[f];
}

// ---------------------------------------------------------------------------
extern "C" void kernel_launch(void* const* d_in, const int* in_sizes, int n_in,
                              void* d_out, int out_size, void* d_ws, size_t ws_size,
                              hipStream_t stream) {
  const float* inp = (const float*)d_in[0];
  const float* T   = (const float*)d_in[1];
  float* out = (float*)d_out;
  char* ws = (char*)d_ws;

  size_t off = 0;
  float*   part = (float*)(ws + off);  off += (size_t)NTn * Bn * Cn * 16 * sizeof(float);   // 36 KB
  __half2* Fxh = (__half2*)(ws + off); off += (size_t)Bn * Cn * KF * Hn * sizeof(__half2);  // 8.5 MB
  float2*  G   = (float2*)(ws + off);  off += (size_t)NTn * Bn * Hn * KGP * sizeof(float2); // 10.0 MB
  __half2* Yh  = (__half2*)(ws + off); off += (size_t)NTn * Bn * Cn * KF * Hn * sizeof(__half2); // 76 MB
  (void)off; (void)ws_size; (void)in_sizes; (void)n_in; (void)out_size;

  k_yrow<<<NTn * Bn * 64, 256, 0, stream>>>(inp, T, Yh, part);
  k_colfft_fx<<<Bn * Cn * KF / 4 / 4, 256, 0, stream>>>(Yh, Fxh);   // 516 blocks
  k_ycol<<<NTn * Bn * 33, 256, 0, stream>>>(Yh, Fxh, part, G);
  k_irow<<<Bn * Hn, 320, 0, stream>>>(G, out);
}

// Round 12
// 169.714 us; speedup vs baseline: 1.0168x; 1.0168x over previous
//
#include <hip/hip_runtime.h>
#include <hip/hip_fp16.h>

#define Bn  4
#define Hn  256
#define Wn  256
#define Cn  16
#define NTn 9
#define HWn (Hn*Wn)
#define KF  129      // W/2 + 1
#define KGP 136      // padded k-row length of G
#define SRL 266      // scratch row length (bank-stagger padded)
#define PI_F 3.14159265358979323846f

// Bank-conflict-free scratch swizzle (R8): p = (i ^ (i>>2)) & 15 is bijective
// on every 16-index subspace the FFT phases use -> exchange phases conflict-
// free (measured 5.35M -> 1.92M conflict cycles; remainder is the store
// phase's inherent 2-way, which is ~free on CDNA4). R11's row-XOR variant
// (SRL=256, 32KB LDS) REVERTED: swizzle address math cost VGPR 88->124,
// dropping waves/SIMD 5->4 and regressing k_yrow 73->99us.
__device__ __forceinline__ int swz(int i) {
  return (i & ~15) | ((i ^ (i >> 2)) & 15);
}

// Natural position of final-radix4 register a: X[dr(lane) + 64a].
__device__ __forceinline__ int drof(int lane) {
  return ((lane & 3) << 4) + (((lane >> 2) & 3) << 2) + (lane >> 4);
}

// Vector-form complex multiply: lowers to v_pk_mul_f32 + v_pk_fma_f32.
__device__ __forceinline__ float2 cmul(float2 a, float2 b) {
  float2 r = make_float2(a.x, a.x) * b;
  return r + make_float2(-a.y, a.y) * make_float2(b.y, b.x);
}

// Vector-form radix-4 butterfly: packed f32 adds (v_pk_add_f32).
template<bool INV>
__device__ __forceinline__ void radix4(float2& x0, float2& x1, float2& x2, float2& x3) {
  float2 y0 = x0 + x2;
  float2 y1 = x0 - x2;
  float2 y2 = x1 + x3;
  float2 y3 = x1 - x3;
  float2 j3 = INV ? make_float2(-y3.y, y3.x) : make_float2(y3.y, -y3.x);
  x0 = y0 + y2;
  x2 = y0 - y2;
  x1 = y1 + j3;   // fwd: y1 - i*y3 ; inv: y1 + i*y3
  x3 = y1 - j3;
}

struct Tw { float2 a1,a2,a3,b1,b2,b3,c1,c2,c3; };

template<bool INV>
__device__ __forceinline__ Tw make_tw(int lane) {
  const float sgn = INV ? 2.0f * PI_F : -2.0f * PI_F;
  Tw t; float sw, cw;
  __sincosf(sgn * (float)lane / 256.0f, &sw, &cw);
  t.a1 = make_float2(cw, sw); t.a2 = cmul(t.a1, t.a1); t.a3 = cmul(t.a2, t.a1);
  __sincosf(sgn * (float)(lane & 15) / 64.0f, &sw, &cw);
  t.b1 = make_float2(cw, sw); t.b2 = cmul(t.b1, t.b1); t.b3 = cmul(t.b2, t.b1);
  __sincosf(sgn * (float)(lane & 3) / 16.0f, &sw, &cw);
  t.c1 = make_float2(cw, sw); t.c2 = cmul(t.c1, t.c1); t.c3 = cmul(t.c2, t.c1);
  return t;
}

// ---------------------------------------------------------------------------
// NF per-wave FFT-256s in LOCKSTEP, ENDING IN REGISTERS (R9): after the call,
// v[f][a] = X_f[drof(lane) + 64a] (permuted lane order, natural freq set per
// lane). Consumers that are elementwise in frequency (spectral products,
// direct coalesced global stores) use this directly and skip the final
// scratch write + read-back. No explicit lgkmcnt drains (R5): DS ops in a
// wave are in-order; compiler inserts counted waits. Cross-wave consumers
// sit behind __syncthreads() in the callers.
// ---------------------------------------------------------------------------
template<bool INV, int NF>
__device__ __forceinline__ void fft256_reg(float2 (*v)[4], float2 (*s)[SRL],
                                           int lane, const Tw& t) {
#pragma unroll
  for (int f = 0; f < NF; ++f) {
    radix4<INV>(v[f][0], v[f][1], v[f][2], v[f][3]);
    v[f][1] = cmul(v[f][1], t.a1); v[f][2] = cmul(v[f][2], t.a2); v[f][3] = cmul(v[f][3], t.a3);
#pragma unroll
    for (int a = 0; a < 4; ++a) s[f][swz(lane + (a << 6))] = v[f][a];
  }
  { int base = (lane >> 4) * 64 + (lane & 15);
#pragma unroll
    for (int f = 0; f < NF; ++f)
#pragma unroll
      for (int a = 0; a < 4; ++a) v[f][a] = s[f][swz(base + (a << 4))];
  }
#pragma unroll
  for (int f = 0; f < NF; ++f) {
    radix4<INV>(v[f][0], v[f][1], v[f][2], v[f][3]);
    v[f][1] = cmul(v[f][1], t.b1); v[f][2] = cmul(v[f][2], t.b2); v[f][3] = cmul(v[f][3], t.b3);
    int base = (lane >> 4) * 64 + (lane & 15);
#pragma unroll
    for (int a = 0; a < 4; ++a) s[f][swz(base + (a << 4))] = v[f][a];
  }
  { int base = (lane >> 4) * 64 + ((lane >> 2) & 3) * 16 + (lane & 3);
#pragma unroll
    for (int f = 0; f < NF; ++f)
#pragma unroll
      for (int a = 0; a < 4; ++a) v[f][a] = s[f][swz(base + (a << 2))];
  }
#pragma unroll
  for (int f = 0; f < NF; ++f) {
    radix4<INV>(v[f][0], v[f][1], v[f][2], v[f][3]);
    v[f][1] = cmul(v[f][1], t.c1); v[f][2] = cmul(v[f][2], t.c2); v[f][3] = cmul(v[f][3], t.c3);
    int base = (lane & ~3) * 4 + (lane & 3);
#pragma unroll
    for (int a = 0; a < 4; ++a) s[f][swz(base + (a << 2))] = v[f][a];
  }
  { int base = lane * 4;
#pragma unroll
    for (int f = 0; f < NF; ++f)
#pragma unroll
      for (int a = 0; a < 4; ++a) v[f][a] = s[f][swz(base + a)];
  }
#pragma unroll
  for (int f = 0; f < NF; ++f)
    radix4<INV>(v[f][0], v[f][1], v[f][2], v[f][3]);
}

// Full variant: natural order in s[f][swz(k)] (needed when another wave or a
// differently-shaped phase consumes the spectrum).
template<bool INV, int NF>
__device__ __forceinline__ void fft256_n(float2 (*v)[4], float2 (*s)[SRL],
                                         int lane, const Tw& t) {
  fft256_reg<INV, NF>(v, s, lane, t);
  int dr = drof(lane);
#pragma unroll
  for (int f = 0; f < NF; ++f)
#pragma unroll
    for (int a = 0; a < 4; ++a) s[f][swz(dr + (a << 6))] = v[f][a];
}

// Inline projective warp map (matches reference: fp-contract off, rintf).
// When 'affine' (wave-uniform), kk == 1.0f exactly for every pixel, so the
// two IEEE divides are skipped bit-exactly.
__device__ __forceinline__ int warp_id2(float a0, float a2, float a3, float a5,
                                        float a6, float p1, float p4, float p7,
                                        bool affine, int col) {
#pragma clang fp contract(off)
  float x = (float)col;
  float xf = (a0 * x + p1) + a2;
  float yf = (a3 * x + p4) + a5;
  if (!affine) {
    float kk = (a6 * x + p7) + 1.0f;
    xf = xf / kk;
    yf = yf / kk;
  }
  float xr = rintf(xf), yr = rintf(yf);
  bool valid = (xr >= 0.f) && (xr < 256.f) && (yr >= 0.f) && (yr < 256.f);
  return valid ? ((int)yr * Wn + (int)xr) : -1;
}

// ---------------------------------------------------------------------------
// Row FFT of warped y (t=0 slab == x spectra). Block = (tb, cg quad, 16-row
// chunk) — NATURAL mapping (R3 XCD-swizzle and R6 cg-fold both regressed:
// concurrent-block locality beats engineered reuse). Half-1 gather issued
// BEFORE half-0's store phase. No min-waves bound (R2 spilled). Keeps the
// full fft256_n: the Hermitian store phase is cross-wave, needs natural
// scratch.
// ---------------------------------------------------------------------------
__global__ __launch_bounds__(256) void k_yrow(const float* __restrict__ inp,
                                              const float* __restrict__ T,
                                              __half2* __restrict__ Yh,
                                              float* __restrict__ part) {
  __shared__ float2 sb[4][4][SRL];
  __shared__ float4 redw[4];
  int tid = threadIdx.x, w = tid >> 6, lane = tid & 63;
  Tw t = make_tw<false>(lane);
  int chunk = blockIdx.x & 15, cg = (blockIdx.x >> 4) & 3, tb = blockIdx.x >> 6;
  int b = tb & 3, tt = tb >> 2;
  int i0 = chunk << 4;
  const float4* ib = (const float4*)(inp + (size_t)b * HWn * Cn);
  float a0, a1, a2, a3, a4, a5, a6, a7;
  { const float* a = T + tt * 8;
    a0=a[0]; a1=a[1]; a2=a[2]; a3=a[3]; a4=a[4]; a5=a[5]; a6=a[6]; a7=a[7]; }
  const bool affine = (fabsf(a6) + fabsf(a7)) * 255.0f < 2.9e-8f;
  float4 nyacc = make_float4(0.f, 0.f, 0.f, 0.f);

  // Hermitian-unpack store phase for half h (reads block-wide scratch).
  auto store_half = [&](int h) {
    int ii = tid & 7, kq = tid >> 3;
    int w2 = ii >> 1, odd = ii & 1;
#pragma unroll
    for (int p = 0; p < 5; ++p) {
      int k = p * 32 + kq;
      if (k <= 128) {
        int kc = (256 - k) & 255;
#pragma unroll
        for (int cc = 0; cc < 4; ++cc) {
          float2 Z  = sb[w2][cc][swz(k)];
          float2 Zc = sb[w2][cc][swz(kc)];
          float2 F = odd ? make_float2(0.5f * (Z.y + Zc.y), 0.5f * (Zc.x - Z.x))
                         : make_float2(0.5f * (Z.x + Zc.x), 0.5f * (Z.y - Zc.y));
          Yh[((size_t)(tb * Cn + cg * 4 + cc) * KF + k) * Hn + i0 + h * 8 + ii] =
              __float22half2_rn(F);
        }
      }
    }
  };

  // ---- half 0: gather + FFT ----
  {
    int r0 = i0 + 2 * w;
    float yA = (float)r0, yB = (float)(r0 + 1);
    float p1A = a1 * yA, p4A = a4 * yA, p7A = a7 * yA;
    float p1B = a1 * yB, p4B = a4 * yB, p7B = a7 * yB;
    float4 g0[4], g1[4];
#pragma unroll
    for (int q = 0; q < 4; ++q) {
      int col = lane + (q << 6);
      int id0 = warp_id2(a0, a2, a3, a5, a6, p1A, p4A, p7A, affine, col);
      int id1 = warp_id2(a0, a2, a3, a5, a6, p1B, p4B, p7B, affine, col);
      g0[q] = (id0 >= 0) ? ib[(size_t)id0 * 4 + cg] : make_float4(0.f,0.f,0.f,0.f);
      g1[q] = (id1 >= 0) ? ib[(size_t)id1 * 4 + cg] : make_float4(0.f,0.f,0.f,0.f);
      nyacc += g0[q] * g0[q] + g1[q] * g1[q];
    }
    float2 v[4][4];
#pragma unroll
    for (int q = 0; q < 4; ++q) {
      v[0][q] = make_float2(g0[q].x, g1[q].x);
      v[1][q] = make_float2(g0[q].y, g1[q].y);
      v[2][q] = make_float2(g0[q].z, g1[q].z);
      v[3][q] = make_float2(g0[q].w, g1[q].w);
    }
    fft256_n<false, 4>(v, sb[w], lane, t);
  }
  __syncthreads();

  // ---- issue half-1 gather NOW: latency hides under half-0 store phase ----
  float4 G0[4], G1[4];
  {
    int r1 = i0 + 8 + 2 * w;
    float yA = (float)r1, yB = (float)(r1 + 1);
    float p1A = a1 * yA, p4A = a4 * yA, p7A = a7 * yA;
    float p1B = a1 * yB, p4B = a4 * yB, p7B = a7 * yB;
#pragma unroll
    for (int q = 0; q < 4; ++q) {
      int col = lane + (q << 6);
      int id0 = warp_id2(a0, a2, a3, a5, a6, p1A, p4A, p7A, affine, col);
      int id1 = warp_id2(a0, a2, a3, a5, a6, p1B, p4B, p7B, affine, col);
      G0[q] = (id0 >= 0) ? ib[(size_t)id0 * 4 + cg] : make_float4(0.f,0.f,0.f,0.f);
      G1[q] = (id1 >= 0) ? ib[(size_t)id1 * 4 + cg] : make_float4(0.f,0.f,0.f,0.f);
    }
  }

  store_half(0);
  __syncthreads();

  // ---- half 1: consume prefetched gather + FFT ----
  {
#pragma unroll
    for (int q = 0; q < 4; ++q)
      nyacc += G0[q] * G0[q] + G1[q] * G1[q];
    float2 v[4][4];
#pragma unroll
    for (int q = 0; q < 4; ++q) {
      v[0][q] = make_float2(G0[q].x, G1[q].x);
      v[1][q] = make_float2(G0[q].y, G1[q].y);
      v[2][q] = make_float2(G0[q].z, G1[q].z);
      v[3][q] = make_float2(G0[q].w, G1[q].w);
    }
    fft256_n<false, 4>(v, sb[w], lane, t);
  }
  __syncthreads();
  store_half(1);

#pragma unroll
  for (int o = 32; o > 0; o >>= 1) {
    nyacc.x += __shfl_down(nyacc.x, o, 64);
    nyacc.y += __shfl_down(nyacc.y, o, 64);
    nyacc.z += __shfl_down(nyacc.z, o, 64);
    nyacc.w += __shfl_down(nyacc.w, o, 64);
  }
  if (lane == 0) redw[w] = nyacc;
  __syncthreads();
  if (tid == 0) {
    float4 s = make_float4(redw[0].x + redw[1].x + redw[2].x + redw[3].x,
                           redw[0].y + redw[1].y + redw[2].y + redw[3].y,
                           redw[0].z + redw[1].z + redw[2].z + redw[3].z,
                           redw[0].w + redw[1].w + redw[2].w + redw[3].w);
    part[((size_t)tb * Cn + cg * 4 + 0) * 16 + chunk] = s.x;
    part[((size_t)tb * Cn + cg * 4 + 1) * 16 + chunk] = s.y;
    part[((size_t)tb * Cn + cg * 4 + 2) * 16 + chunk] = s.z;
    part[((size_t)tb * Cn + cg * 4 + 3) * 16 + chunk] = s.w;
  }
}

// ---------------------------------------------------------------------------
// Column FFT of x spectra, q4-batched. R9: spectrum stays in registers; the
// output store goes directly to Fxh[dr+64a] (coalescing is by address, so
// the lane permutation is free) — final scratch write + read-back removed.
// ---------------------------------------------------------------------------
__global__ __launch_bounds__(256) void k_colfft_fx(const __half2* __restrict__ Yh,
                                                   __half2* __restrict__ Fxh) {
  __shared__ float2 sb[4][4][SRL];
  int tid = threadIdx.x, w = tid >> 6, lane = tid & 63;
  Tw t = make_tw<false>(lane);
  int base_item = blockIdx.x * 16 + w * 4;   // (b*16+c)*KF + k
  float2 v[4][4];
#pragma unroll
  for (int f = 0; f < 4; ++f) {
    const __half2* Sp = Yh + (size_t)(base_item + f) * Hn;
#pragma unroll
    for (int q = 0; q < 4; ++q) v[f][q] = __half22float2(Sp[lane + (q << 6)]);
  }
  fft256_reg<false, 4>(v, sb[w], lane, t);
  int dr = drof(lane);
#pragma unroll
  for (int f = 0; f < 4; ++f) {
    __half2* Op = Fxh + (size_t)(base_item + f) * Hn;
#pragma unroll
    for (int a = 0; a < 4; ++a)
      Op[dr + (a << 6)] = __float22half2_rn(v[f][a]);
  }
}

// ---------------------------------------------------------------------------
// Block = (tb, k-quartet). R9: forward FFTs end in registers; the spectral
// product + c-sum is elementwise in frequency, so it runs in PERMUTED order
// (fx read at dr+64a — coalesced, address-based). One 8-op scratch roundtrip
// restores natural lane order for the inverse FFT. t=0 shortcut (R7) kept.
// ---------------------------------------------------------------------------
__global__ __launch_bounds__(256) void k_ycol(const __half2* __restrict__ Yh,
                                              const __half2* __restrict__ Fxh,
                                              const float* __restrict__ part,
                                              float2* __restrict__ G) {
  __shared__ float2 sb[4][4][SRL];
  __shared__ float scs[16];
  int tid = threadIdx.x, w = tid >> 6, lane = tid & 63;
  int tb = blockIdx.x / 33, quart = blockIdx.x % 33;
  int b = tb & 3;
  int k = quart * 4 + w;
  bool act = (k <= 128);
  bool t0 = (tb < 4);                         // tt == 0: identity transform
  const __half2* Ybase = Yh  + ((size_t)(tb * Cn) * KF + k) * Hn;
  const __half2* Fbase = Fxh + ((size_t)(b  * Cn) * KF + k) * Hn;

  float2 va[4][4], vb[4][4];
  auto LOADY = [&](float2 (*v)[4], int c0) {
#pragma unroll
    for (int e = 0; e < 4; ++e) {
      const __half2* Yp = Ybase + (size_t)(c0 + e) * KF * Hn;
#pragma unroll
      for (int q = 0; q < 4; ++q) v[e][q] = __half22float2(Yp[lane + (q << 6)]);
    }
  };
  if (act && !t0) LOADY(va, 0);   // latency hides under scs reduce + barrier

  if (tid < 16) {
    float sx = 0.f, sy = 0.f;
#pragma unroll
    for (int ch = 0; ch < 16; ++ch) {
      sx += part[((size_t)b  * Cn + tid) * 16 + ch];   // t=0 slab == x norms
      sy += part[((size_t)tb * Cn + tid) * 16 + ch];
    }
    scs[tid] = 1.0f / ((float)Cn * (sqrtf(sx) * sqrtf(sy) + 1e-12f));
  }
  __syncthreads();

  if (act) {
    int dr = drof(lane);
    if (!t0) {
      Tw tf = make_tw<false>(lane);
      float2 accp[4];
#pragma unroll
      for (int a = 0; a < 4; ++a) accp[a] = make_float2(0.f, 0.f);
      // fy in regs: vv[e][a] = Fy_e[dr + 64a]; fx read at the same freqs.
      auto ACCP = [&](float2 (*vv)[4], int c0) {
#pragma unroll
        for (int e = 0; e < 4; ++e) {
          float sc = scs[c0 + e];
          const __half2* Fxp = Fbase + (size_t)(c0 + e) * KF * Hn;
#pragma unroll
          for (int a = 0; a < 4; ++a) {
            float2 fy = vv[e][a];
            float2 fx = __half22float2(Fxp[dr + (a << 6)]);
            // fx * conj(fy), packed-f32 form
            float2 pr = make_float2(fy.x, fy.x) * fx
                      + make_float2(fy.y, fy.y) * make_float2(fx.y, -fx.x);
            accp[a] += make_float2(sc, sc) * pr;
          }
        }
      };
      fft256_reg<false, 4>(va, sb[w], lane, tf);  LOADY(vb, 4);   ACCP(va, 0);
      fft256_reg<false, 4>(vb, sb[w], lane, tf);  LOADY(va, 8);   ACCP(vb, 4);
      fft256_reg<false, 4>(va, sb[w], lane, tf);  LOADY(vb, 12);  ACCP(va, 8);
      fft256_reg<false, 4>(vb, sb[w], lane, tf);                  ACCP(vb, 12);
      // permuted -> natural roundtrip (wave-private, in-order DS)
#pragma unroll
      for (int a = 0; a < 4; ++a) sb[w][0][swz(dr + (a << 6))] = accp[a];
      float2 v0[1][4];
#pragma unroll
      for (int a = 0; a < 4; ++a) v0[0][a] = sb[w][0][swz(lane + (a << 6))];
      Tw ti = make_tw<true>(lane);
      fft256_n<true, 1>(v0, sb[w], lane, ti);
    } else {
      // t=0: corr spectrum = sum_c sc_c * |fx_c|^2 (purely real), natural order
      float2 acc[1][4];
#pragma unroll
      for (int q = 0; q < 4; ++q) acc[0][q] = make_float2(0.f, 0.f);
#pragma unroll
      for (int c = 0; c < Cn; ++c) {
        float sc = scs[c];
        const __half2* Fxp = Fbase + (size_t)c * KF * Hn;
#pragma unroll
        for (int q = 0; q < 4; ++q) {
          float2 fx = __half22float2(Fxp[lane + (q << 6)]);
          acc[0][q].x += sc * (fx.x * fx.x + fx.y * fx.y);
        }
      }
      Tw ti = make_tw<true>(lane);
      fft256_n<true, 1>(acc, sb[w], lane, ti);
    }
  }
  __syncthreads();
  // transposed store: 4 consecutive k per j -> 32B granules
  int kk = tid & 3, jj0 = tid >> 2;
  if (quart * 4 + kk <= 128) {
    float2* Gp = G + ((size_t)tb * Hn) * KGP + quart * 4 + kk;
#pragma unroll
    for (int p = 0; p < 4; ++p) {
      int j = jj0 + (p << 6);
      Gp[(size_t)j * KGP] = sb[kk][0][swz(j)];
    }
  }
}

// ---------------------------------------------------------------------------
// Final pass: block = (b, spatial row i), 5 waves. R9: inverse FFT ends in
// registers; rowbuf written directly at j = dr+64a (same LDS scatter profile
// as before), skipping the final scratch write + read-back.
// ---------------------------------------------------------------------------
__global__ __launch_bounds__(320) void k_irow(const float2* __restrict__ G,
                                              float* __restrict__ out) {
  __shared__ float2 tile[5][2][132];
  __shared__ float2 sb[5][SRL];
  __shared__ float rowbuf[Wn * NTn];
  int tid = threadIdx.x, w = tid >> 6, lane = tid & 63;
  Tw ti = make_tw<true>(lane);
  int b = blockIdx.x >> 8, i = blockIdx.x & 255;
  const float scale = 1.0f / ((float)Hn * (float)Wn);
  int t1 = 2 * w, t2 = t1 + 1;
  {
    const float2* Gp1 = G + ((size_t)(t1 * Bn + b) * Hn + i) * KGP;
    for (int k = lane; k < KF; k += 64) tile[w][0][k] = Gp1[k];
    if (t2 < NTn) {
      const float2* Gp2 = G + ((size_t)(t2 * Bn + b) * Hn + i) * KGP;
      for (int k = lane; k < KF; k += 64) tile[w][1][k] = Gp2[k];
    }
  }
  // tile[w] is wave-private; DS in-order + compiler waits handle the reads.
  float2 v[1][4];
#pragma unroll
  for (int q = 0; q < 4; ++q) {
    int k = lane + (q << 6);
    float2 a, bb;
    if (k <= 128) a = tile[w][0][k];
    else { float2 z = tile[w][0][256 - k]; a = make_float2(z.x, -z.y); }
    if (t2 < NTn) {
      if (k <= 128) bb = tile[w][1][k];
      else { float2 z = tile[w][1][256 - k]; bb = make_float2(z.x, -z.y); }
    } else bb = make_float2(0.f, 0.f);
    v[0][q] = a + make_float2(-bb.y, bb.x);   // A + i*B, packed add
  }
  fft256_reg<true, 1>(v, reinterpret_cast<float2(*)[SRL]>(sb[w]), lane, ti);
  int dr = drof(lane);
#pragma unroll
  for (int a = 0; a < 4; ++a) {
    int j = dr + (a << 6);
    rowbuf[j * NTn + t1] = v[0][a].x * scale;
    if (t2 < NTn) rowbuf[j * NTn + t2] = v[0][a].y * scale;
  }
  __syncthreads();
  float* ob = out + ((size_t)(b * Hn + i) * Wn) * NTn;
  for (int f = tid; f < Wn * NTn; f += 320) ob[f] = rowbuf[f];
}

// ---------------------------------------------------------------------------
extern "C" void kernel_launch(void* const* d_in, const int* in_sizes, int n_in,
                              void* d_out, int out_size, void* d_ws, size_t ws_size,
                              hipStream_t stream) {
  const float* inp = (const float*)d_in[0];
  const float* T   = (const float*)d_in[1];
  float* out = (float*)d_out;
  char* ws = (char*)d_ws;

  size_t off = 0;
  float*   part = (float*)(ws + off);  off += (size_t)NTn * Bn * Cn * 16 * sizeof(float);   // 36 KB
  __half2* Fxh = (__half2*)(ws + off); off += (size_t)Bn * Cn * KF * Hn * sizeof(__half2);  // 8.5 MB
  float2*  G   = (float2*)(ws + off);  off += (size_t)NTn * Bn * Hn * KGP * sizeof(float2); // 10.0 MB
  __half2* Yh  = (__half2*)(ws + off); off += (size_t)NTn * Bn * Cn * KF * Hn * sizeof(__half2); // 76 MB
  (void)off; (void)ws_size; (void)in_sizes; (void)n_in; (void)out_size;

  k_yrow<<<NTn * Bn * 64, 256, 0, stream>>>(inp, T, Yh, part);
  k_colfft_fx<<<Bn * Cn * KF / 4 / 4, 256, 0, stream>>>(Yh, Fxh);   // 516 blocks
  k_ycol<<<NTn * Bn * 33, 256, 0, stream>>>(Yh, Fxh, part, G);
  k_irow<<<Bn * Hn, 320, 0, stream>>>(G, out);
}

// Round 13
// 162.027 us; speedup vs baseline: 1.0650x; 1.0474x over previous
//
#include <hip/hip_runtime.h>
#include <hip/hip_fp16.h>

#define Bn  4
#define Hn  256
#define Wn  256
#define Cn  16
#define NTn 9
#define HWn (Hn*Wn)
#define KF  129      // W/2 + 1
#define KGP 136      // padded k-row length of G
#define SRL 266      // scratch row length (bank-stagger padded)
#define PI_F 3.14159265358979323846f

// Bank-conflict-free scratch swizzle (R8): p = (i ^ (i>>2)) & 15 is bijective
// on every 16-index subspace the FFT phases use -> exchange phases conflict-
// free (measured 5.35M -> 1.92M conflict cycles; remainder is the store
// phase's inherent 2-way, which is ~free on CDNA4). R11's row-XOR variant
// (SRL=256, 32KB LDS) REVERTED: swizzle address math cost VGPR 88->124,
// dropping waves/SIMD 5->4 and regressing k_yrow 73->99us.
__device__ __forceinline__ int swz(int i) {
  return (i & ~15) | ((i ^ (i >> 2)) & 15);
}

// Natural position of final-radix4 register a: X[dr(lane) + 64a].
__device__ __forceinline__ int drof(int lane) {
  return ((lane & 3) << 4) + (((lane >> 2) & 3) << 2) + (lane >> 4);
}

// Vector-form complex multiply: lowers to v_pk_mul_f32 + v_pk_fma_f32.
__device__ __forceinline__ float2 cmul(float2 a, float2 b) {
  float2 r = make_float2(a.x, a.x) * b;
  return r + make_float2(-a.y, a.y) * make_float2(b.y, b.x);
}

// Vector-form radix-4 butterfly: packed f32 adds (v_pk_add_f32).
template<bool INV>
__device__ __forceinline__ void radix4(float2& x0, float2& x1, float2& x2, float2& x3) {
  float2 y0 = x0 + x2;
  float2 y1 = x0 - x2;
  float2 y2 = x1 + x3;
  float2 y3 = x1 - x3;
  float2 j3 = INV ? make_float2(-y3.y, y3.x) : make_float2(y3.y, -y3.x);
  x0 = y0 + y2;
  x2 = y0 - y2;
  x1 = y1 + j3;   // fwd: y1 - i*y3 ; inv: y1 + i*y3
  x3 = y1 - j3;
}

struct Tw { float2 a1,a2,a3,b1,b2,b3,c1,c2,c3; };

template<bool INV>
__device__ __forceinline__ Tw make_tw(int lane) {
  const float sgn = INV ? 2.0f * PI_F : -2.0f * PI_F;
  Tw t; float sw, cw;
  __sincosf(sgn * (float)lane / 256.0f, &sw, &cw);
  t.a1 = make_float2(cw, sw); t.a2 = cmul(t.a1, t.a1); t.a3 = cmul(t.a2, t.a1);
  __sincosf(sgn * (float)(lane & 15) / 64.0f, &sw, &cw);
  t.b1 = make_float2(cw, sw); t.b2 = cmul(t.b1, t.b1); t.b3 = cmul(t.b2, t.b1);
  __sincosf(sgn * (float)(lane & 3) / 16.0f, &sw, &cw);
  t.c1 = make_float2(cw, sw); t.c2 = cmul(t.c1, t.c1); t.c3 = cmul(t.c2, t.c1);
  return t;
}

// ---------------------------------------------------------------------------
// NF per-wave FFT-256s in LOCKSTEP, ENDING IN REGISTERS (R9): after the call,
// v[f][a] = X_f[drof(lane) + 64a] (permuted lane order, natural freq set per
// lane). Consumers that are elementwise in frequency (spectral products,
// direct coalesced global stores) use this directly and skip the final
// scratch write + read-back. No explicit lgkmcnt drains (R5): DS ops in a
// wave are in-order; compiler inserts counted waits. Cross-wave consumers
// sit behind __syncthreads() in the callers.
// ---------------------------------------------------------------------------
template<bool INV, int NF>
__device__ __forceinline__ void fft256_reg(float2 (*v)[4], float2 (*s)[SRL],
                                           int lane, const Tw& t) {
#pragma unroll
  for (int f = 0; f < NF; ++f) {
    radix4<INV>(v[f][0], v[f][1], v[f][2], v[f][3]);
    v[f][1] = cmul(v[f][1], t.a1); v[f][2] = cmul(v[f][2], t.a2); v[f][3] = cmul(v[f][3], t.a3);
#pragma unroll
    for (int a = 0; a < 4; ++a) s[f][swz(lane + (a << 6))] = v[f][a];
  }
  { int base = (lane >> 4) * 64 + (lane & 15);
#pragma unroll
    for (int f = 0; f < NF; ++f)
#pragma unroll
      for (int a = 0; a < 4; ++a) v[f][a] = s[f][swz(base + (a << 4))];
  }
#pragma unroll
  for (int f = 0; f < NF; ++f) {
    radix4<INV>(v[f][0], v[f][1], v[f][2], v[f][3]);
    v[f][1] = cmul(v[f][1], t.b1); v[f][2] = cmul(v[f][2], t.b2); v[f][3] = cmul(v[f][3], t.b3);
    int base = (lane >> 4) * 64 + (lane & 15);
#pragma unroll
    for (int a = 0; a < 4; ++a) s[f][swz(base + (a << 4))] = v[f][a];
  }
  { int base = (lane >> 4) * 64 + ((lane >> 2) & 3) * 16 + (lane & 3);
#pragma unroll
    for (int f = 0; f < NF; ++f)
#pragma unroll
      for (int a = 0; a < 4; ++a) v[f][a] = s[f][swz(base + (a << 2))];
  }
#pragma unroll
  for (int f = 0; f < NF; ++f) {
    radix4<INV>(v[f][0], v[f][1], v[f][2], v[f][3]);
    v[f][1] = cmul(v[f][1], t.c1); v[f][2] = cmul(v[f][2], t.c2); v[f][3] = cmul(v[f][3], t.c3);
    int base = (lane & ~3) * 4 + (lane & 3);
#pragma unroll
    for (int a = 0; a < 4; ++a) s[f][swz(base + (a << 2))] = v[f][a];
  }
  { int base = lane * 4;
#pragma unroll
    for (int f = 0; f < NF; ++f)
#pragma unroll
      for (int a = 0; a < 4; ++a) v[f][a] = s[f][swz(base + a)];
  }
#pragma unroll
  for (int f = 0; f < NF; ++f)
    radix4<INV>(v[f][0], v[f][1], v[f][2], v[f][3]);
}

// Full variant: natural order in s[f][swz(k)] (needed when another wave or a
// differently-shaped phase consumes the spectrum).
template<bool INV, int NF>
__device__ __forceinline__ void fft256_n(float2 (*v)[4], float2 (*s)[SRL],
                                         int lane, const Tw& t) {
  fft256_reg<INV, NF>(v, s, lane, t);
  int dr = drof(lane);
#pragma unroll
  for (int f = 0; f < NF; ++f)
#pragma unroll
    for (int a = 0; a < 4; ++a) s[f][swz(dr + (a << 6))] = v[f][a];
}

// Inline projective warp map (matches reference: fp-contract off, rintf).
// When 'affine' (wave-uniform), kk == 1.0f exactly for every pixel, so the
// two IEEE divides are skipped bit-exactly.
__device__ __forceinline__ int warp_id2(float a0, float a2, float a3, float a5,
                                        float a6, float p1, float p4, float p7,
                                        bool affine, int col) {
#pragma clang fp contract(off)
  float x = (float)col;
  float xf = (a0 * x + p1) + a2;
  float yf = (a3 * x + p4) + a5;
  if (!affine) {
    float kk = (a6 * x + p7) + 1.0f;
    xf = xf / kk;
    yf = yf / kk;
  }
  float xr = rintf(xf), yr = rintf(yf);
  bool valid = (xr >= 0.f) && (xr < 256.f) && (yr >= 0.f) && (yr < 256.f);
  return valid ? ((int)yr * Wn + (int)xr) : -1;
}

// ---------------------------------------------------------------------------
// Row FFT of warped y (t=0 slab == x spectra). Block = (tb, cg quad, 16-row
// chunk) — NATURAL mapping (R3 XCD-swizzle and R6 cg-fold both regressed:
// concurrent-block locality beats engineered reuse). Half-1 gather issued
// BEFORE half-0's unpack phase. No min-waves bound (R2 spilled).
// R13: DEFERRED STORE — half-0's Hermitian-unpacked values are stashed in
// 20 VGPRs (__half2 Fs[5][4]) instead of stored; after the half-1 FFT both
// halves are written back-to-back so each 64B Yh line (16 half2 along i) is
// fully covered in one window. Removes the measured ~25% write amplification
// (WRITE_SIZE 96-100MB vs 76MB ideal) caused by the two 32B half-line writes
// being separated by an FFT + 2 barriers (line evicted between halves).
// ---------------------------------------------------------------------------
__global__ __launch_bounds__(256) void k_yrow(const float* __restrict__ inp,
                                              const float* __restrict__ T,
                                              __half2* __restrict__ Yh,
                                              float* __restrict__ part) {
  __shared__ float2 sb[4][4][SRL];
  __shared__ float4 redw[4];
  int tid = threadIdx.x, w = tid >> 6, lane = tid & 63;
  Tw t = make_tw<false>(lane);
  int chunk = blockIdx.x & 15, cg = (blockIdx.x >> 4) & 3, tb = blockIdx.x >> 6;
  int b = tb & 3, tt = tb >> 2;
  int i0 = chunk << 4;
  const float4* ib = (const float4*)(inp + (size_t)b * HWn * Cn);
  float a0, a1, a2, a3, a4, a5, a6, a7;
  { const float* a = T + tt * 8;
    a0=a[0]; a1=a[1]; a2=a[2]; a3=a[3]; a4=a[4]; a5=a[5]; a6=a[6]; a7=a[7]; }
  const bool affine = (fabsf(a6) + fabsf(a7)) * 255.0f < 2.9e-8f;
  float4 nyacc = make_float4(0.f, 0.f, 0.f, 0.f);

  // Hermitian-unpack for (k, cc) from block-wide scratch (this thread's role:
  // ii = row-within-half, kq = k-octet).
  int ii = tid & 7, kq = tid >> 3;
  int w2 = ii >> 1, odd = ii & 1;
  auto calc_F = [&](int k, int cc) -> float2 {
    int kc = (256 - k) & 255;
    float2 Z  = sb[w2][cc][swz(k)];
    float2 Zc = sb[w2][cc][swz(kc)];
    return odd ? make_float2(0.5f * (Z.y + Zc.y), 0.5f * (Zc.x - Z.x))
               : make_float2(0.5f * (Z.x + Zc.x), 0.5f * (Z.y - Zc.y));
  };

  // ---- half 0: gather + FFT ----
  {
    int r0 = i0 + 2 * w;
    float yA = (float)r0, yB = (float)(r0 + 1);
    float p1A = a1 * yA, p4A = a4 * yA, p7A = a7 * yA;
    float p1B = a1 * yB, p4B = a4 * yB, p7B = a7 * yB;
    float4 g0[4], g1[4];
#pragma unroll
    for (int q = 0; q < 4; ++q) {
      int col = lane + (q << 6);
      int id0 = warp_id2(a0, a2, a3, a5, a6, p1A, p4A, p7A, affine, col);
      int id1 = warp_id2(a0, a2, a3, a5, a6, p1B, p4B, p7B, affine, col);
      g0[q] = (id0 >= 0) ? ib[(size_t)id0 * 4 + cg] : make_float4(0.f,0.f,0.f,0.f);
      g1[q] = (id1 >= 0) ? ib[(size_t)id1 * 4 + cg] : make_float4(0.f,0.f,0.f,0.f);
      nyacc += g0[q] * g0[q] + g1[q] * g1[q];
    }
    float2 v[4][4];
#pragma unroll
    for (int q = 0; q < 4; ++q) {
      v[0][q] = make_float2(g0[q].x, g1[q].x);
      v[1][q] = make_float2(g0[q].y, g1[q].y);
      v[2][q] = make_float2(g0[q].z, g1[q].z);
      v[3][q] = make_float2(g0[q].w, g1[q].w);
    }
    fft256_n<false, 4>(v, sb[w], lane, t);
  }
  __syncthreads();

  // ---- issue half-1 gather NOW: latency hides under half-0 unpack phase ----
  float4 G0[4], G1[4];
  {
    int r1 = i0 + 8 + 2 * w;
    float yA = (float)r1, yB = (float)(r1 + 1);
    float p1A = a1 * yA, p4A = a4 * yA, p7A = a7 * yA;
    float p1B = a1 * yB, p4B = a4 * yB, p7B = a7 * yB;
#pragma unroll
    for (int q = 0; q < 4; ++q) {
      int col = lane + (q << 6);
      int id0 = warp_id2(a0, a2, a3, a5, a6, p1A, p4A, p7A, affine, col);
      int id1 = warp_id2(a0, a2, a3, a5, a6, p1B, p4B, p7B, affine, col);
      G0[q] = (id0 >= 0) ? ib[(size_t)id0 * 4 + cg] : make_float4(0.f,0.f,0.f,0.f);
      G1[q] = (id1 >= 0) ? ib[(size_t)id1 * 4 + cg] : make_float4(0.f,0.f,0.f,0.f);
    }
  }

  // ---- half-0 unpack: stash in registers (no global store yet) ----
  __half2 Fs[5][4];
#pragma unroll
  for (int p = 0; p < 5; ++p) {
    int k = p * 32 + kq;
    if (k <= 128) {
#pragma unroll
      for (int cc = 0; cc < 4; ++cc)
        Fs[p][cc] = __float22half2_rn(calc_F(k, cc));
    }
  }
  __syncthreads();

  // ---- half 1: consume prefetched gather + FFT ----
  {
#pragma unroll
    for (int q = 0; q < 4; ++q)
      nyacc += G0[q] * G0[q] + G1[q] * G1[q];
    float2 v[4][4];
#pragma unroll
    for (int q = 0; q < 4; ++q) {
      v[0][q] = make_float2(G0[q].x, G1[q].x);
      v[1][q] = make_float2(G0[q].y, G1[q].y);
      v[2][q] = make_float2(G0[q].z, G1[q].z);
      v[3][q] = make_float2(G0[q].w, G1[q].w);
    }
    fft256_n<false, 4>(v, sb[w], lane, t);
  }
  __syncthreads();

  // ---- combined store: both halves of each 64B line back-to-back ----
#pragma unroll
  for (int p = 0; p < 5; ++p) {
    int k = p * 32 + kq;
    if (k <= 128) {
#pragma unroll
      for (int cc = 0; cc < 4; ++cc) {
        float2 F1 = calc_F(k, cc);
        __half2* Yp = Yh + ((size_t)(tb * Cn + cg * 4 + cc) * KF + k) * Hn + i0 + ii;
        Yp[0] = Fs[p][cc];
        Yp[8] = __float22half2_rn(F1);
      }
    }
  }

#pragma unroll
  for (int o = 32; o > 0; o >>= 1) {
    nyacc.x += __shfl_down(nyacc.x, o, 64);
    nyacc.y += __shfl_down(nyacc.y, o, 64);
    nyacc.z += __shfl_down(nyacc.z, o, 64);
    nyacc.w += __shfl_down(nyacc.w, o, 64);
  }
  if (lane == 0) redw[w] = nyacc;
  __syncthreads();
  if (tid == 0) {
    float4 s = make_float4(redw[0].x + redw[1].x + redw[2].x + redw[3].x,
                           redw[0].y + redw[1].y + redw[2].y + redw[3].y,
                           redw[0].z + redw[1].z + redw[2].z + redw[3].z,
                           redw[0].w + redw[1].w + redw[2].w + redw[3].w);
    part[((size_t)tb * Cn + cg * 4 + 0) * 16 + chunk] = s.x;
    part[((size_t)tb * Cn + cg * 4 + 1) * 16 + chunk] = s.y;
    part[((size_t)tb * Cn + cg * 4 + 2) * 16 + chunk] = s.z;
    part[((size_t)tb * Cn + cg * 4 + 3) * 16 + chunk] = s.w;
  }
}

// ---------------------------------------------------------------------------
// Column FFT of x spectra, q4-batched. R9: spectrum stays in registers; the
// output store goes directly to Fxh[dr+64a] (coalescing is by address, so
// the lane permutation is free) — final scratch write + read-back removed.
// ---------------------------------------------------------------------------
__global__ __launch_bounds__(256) void k_colfft_fx(const __half2* __restrict__ Yh,
                                                   __half2* __restrict__ Fxh) {
  __shared__ float2 sb[4][4][SRL];
  int tid = threadIdx.x, w = tid >> 6, lane = tid & 63;
  Tw t = make_tw<false>(lane);
  int base_item = blockIdx.x * 16 + w * 4;   // (b*16+c)*KF + k
  float2 v[4][4];
#pragma unroll
  for (int f = 0; f < 4; ++f) {
    const __half2* Sp = Yh + (size_t)(base_item + f) * Hn;
#pragma unroll
    for (int q = 0; q < 4; ++q) v[f][q] = __half22float2(Sp[lane + (q << 6)]);
  }
  fft256_reg<false, 4>(v, sb[w], lane, t);
  int dr = drof(lane);
#pragma unroll
  for (int f = 0; f < 4; ++f) {
    __half2* Op = Fxh + (size_t)(base_item + f) * Hn;
#pragma unroll
    for (int a = 0; a < 4; ++a)
      Op[dr + (a << 6)] = __float22half2_rn(v[f][a]);
  }
}

// ---------------------------------------------------------------------------
// Block = (tb, k-quartet). R9: forward FFTs end in registers; the spectral
// product + c-sum is elementwise in frequency, so it runs in PERMUTED order
// (fx read at dr+64a — coalesced, address-based). One 8-op scratch roundtrip
// restores natural lane order for the inverse FFT. t=0 shortcut (R7) kept.
// ---------------------------------------------------------------------------
__global__ __launch_bounds__(256) void k_ycol(const __half2* __restrict__ Yh,
                                              const __half2* __restrict__ Fxh,
                                              const float* __restrict__ part,
                                              float2* __restrict__ G) {
  __shared__ float2 sb[4][4][SRL];
  __shared__ float scs[16];
  int tid = threadIdx.x, w = tid >> 6, lane = tid & 63;
  int tb = blockIdx.x / 33, quart = blockIdx.x % 33;
  int b = tb & 3;
  int k = quart * 4 + w;
  bool act = (k <= 128);
  bool t0 = (tb < 4);                         // tt == 0: identity transform
  const __half2* Ybase = Yh  + ((size_t)(tb * Cn) * KF + k) * Hn;
  const __half2* Fbase = Fxh + ((size_t)(b  * Cn) * KF + k) * Hn;

  float2 va[4][4], vb[4][4];
  auto LOADY = [&](float2 (*v)[4], int c0) {
#pragma unroll
    for (int e = 0; e < 4; ++e) {
      const __half2* Yp = Ybase + (size_t)(c0 + e) * KF * Hn;
#pragma unroll
      for (int q = 0; q < 4; ++q) v[e][q] = __half22float2(Yp[lane + (q << 6)]);
    }
  };
  if (act && !t0) LOADY(va, 0);   // latency hides under scs reduce + barrier

  if (tid < 16) {
    float sx = 0.f, sy = 0.f;
#pragma unroll
    for (int ch = 0; ch < 16; ++ch) {
      sx += part[((size_t)b  * Cn + tid) * 16 + ch];   // t=0 slab == x norms
      sy += part[((size_t)tb * Cn + tid) * 16 + ch];
    }
    scs[tid] = 1.0f / ((float)Cn * (sqrtf(sx) * sqrtf(sy) + 1e-12f));
  }
  __syncthreads();

  if (act) {
    int dr = drof(lane);
    if (!t0) {
      Tw tf = make_tw<false>(lane);
      float2 accp[4];
#pragma unroll
      for (int a = 0; a < 4; ++a) accp[a] = make_float2(0.f, 0.f);
      // fy in regs: vv[e][a] = Fy_e[dr + 64a]; fx read at the same freqs.
      auto ACCP = [&](float2 (*vv)[4], int c0) {
#pragma unroll
        for (int e = 0; e < 4; ++e) {
          float sc = scs[c0 + e];
          const __half2* Fxp = Fbase + (size_t)(c0 + e) * KF * Hn;
#pragma unroll
          for (int a = 0; a < 4; ++a) {
            float2 fy = vv[e][a];
            float2 fx = __half22float2(Fxp[dr + (a << 6)]);
            // fx * conj(fy), packed-f32 form
            float2 pr = make_float2(fy.x, fy.x) * fx
                      + make_float2(fy.y, fy.y) * make_float2(fx.y, -fx.x);
            accp[a] += make_float2(sc, sc) * pr;
          }
        }
      };
      fft256_reg<false, 4>(va, sb[w], lane, tf);  LOADY(vb, 4);   ACCP(va, 0);
      fft256_reg<false, 4>(vb, sb[w], lane, tf);  LOADY(va, 8);   ACCP(vb, 4);
      fft256_reg<false, 4>(va, sb[w], lane, tf);  LOADY(vb, 12);  ACCP(va, 8);
      fft256_reg<false, 4>(vb, sb[w], lane, tf);                  ACCP(vb, 12);
      // permuted -> natural roundtrip (wave-private, in-order DS)
#pragma unroll
      for (int a = 0; a < 4; ++a) sb[w][0][swz(dr + (a << 6))] = accp[a];
      float2 v0[1][4];
#pragma unroll
      for (int a = 0; a < 4; ++a) v0[0][a] = sb[w][0][swz(lane + (a << 6))];
      Tw ti = make_tw<true>(lane);
      fft256_n<true, 1>(v0, sb[w], lane, ti);
    } else {
      // t=0: corr spectrum = sum_c sc_c * |fx_c|^2 (purely real), natural order
      float2 acc[1][4];
#pragma unroll
      for (int q = 0; q < 4; ++q) acc[0][q] = make_float2(0.f, 0.f);
#pragma unroll
      for (int c = 0; c < Cn; ++c) {
        float sc = scs[c];
        const __half2* Fxp = Fbase + (size_t)c * KF * Hn;
#pragma unroll
        for (int q = 0; q < 4; ++q) {
          float2 fx = __half22float2(Fxp[lane + (q << 6)]);
          acc[0][q].x += sc * (fx.x * fx.x + fx.y * fx.y);
        }
      }
      Tw ti = make_tw<true>(lane);
      fft256_n<true, 1>(acc, sb[w], lane, ti);
    }
  }
  __syncthreads();
  // transposed store: 4 consecutive k per j -> 32B granules
  int kk = tid & 3, jj0 = tid >> 2;
  if (quart * 4 + kk <= 128) {
    float2* Gp = G + ((size_t)tb * Hn) * KGP + quart * 4 + kk;
#pragma unroll
    for (int p = 0; p < 4; ++p) {
      int j = jj0 + (p << 6);
      Gp[(size_t)j * KGP] = sb[kk][0][swz(j)];
    }
  }
}

// ---------------------------------------------------------------------------
// Final pass: block = (b, spatial row i), 5 waves. R9: inverse FFT ends in
// registers; rowbuf written directly at j = dr+64a (same LDS scatter profile
// as before), skipping the final scratch write + read-back.
// ---------------------------------------------------------------------------
__global__ __launch_bounds__(320) void k_irow(const float2* __restrict__ G,
                                              float* __restrict__ out) {
  __shared__ float2 tile[5][2][132];
  __shared__ float2 sb[5][SRL];
  __shared__ float rowbuf[Wn * NTn];
  int tid = threadIdx.x, w = tid >> 6, lane = tid & 63;
  Tw ti = make_tw<true>(lane);
  int b = blockIdx.x >> 8, i = blockIdx.x & 255;
  const float scale = 1.0f / ((float)Hn * (float)Wn);
  int t1 = 2 * w, t2 = t1 + 1;
  {
    const float2* Gp1 = G + ((size_t)(t1 * Bn + b) * Hn + i) * KGP;
    for (int k = lane; k < KF; k += 64) tile[w][0][k] = Gp1[k];
    if (t2 < NTn) {
      const float2* Gp2 = G + ((size_t)(t2 * Bn + b) * Hn + i) * KGP;
      for (int k = lane; k < KF; k += 64) tile[w][1][k] = Gp2[k];
    }
  }
  // tile[w] is wave-private; DS in-order + compiler waits handle the reads.
  float2 v[1][4];
#pragma unroll
  for (int q = 0; q < 4; ++q) {
    int k = lane + (q << 6);
    float2 a, bb;
    if (k <= 128) a = tile[w][0][k];
    else { float2 z = tile[w][0][256 - k]; a = make_float2(z.x, -z.y); }
    if (t2 < NTn) {
      if (k <= 128) bb = tile[w][1][k];
      else { float2 z = tile[w][1][256 - k]; bb = make_float2(z.x, -z.y); }
    } else bb = make_float2(0.f, 0.f);
    v[0][q] = a + make_float2(-bb.y, bb.x);   // A + i*B, packed add
  }
  fft256_reg<true, 1>(v, reinterpret_cast<float2(*)[SRL]>(sb[w]), lane, ti);
  int dr = drof(lane);
#pragma unroll
  for (int a = 0; a < 4; ++a) {
    int j = dr + (a << 6);
    rowbuf[j * NTn + t1] = v[0][a].x * scale;
    if (t2 < NTn) rowbuf[j * NTn + t2] = v[0][a].y * scale;
  }
  __syncthreads();
  float* ob = out + ((size_t)(b * Hn + i) * Wn) * NTn;
  for (int f = tid; f < Wn * NTn; f += 320) ob[f] = rowbuf[f];
}

// ---------------------------------------------------------------------------
extern "C" void kernel_launch(void* const* d_in, const int* in_sizes, int n_in,
                              void* d_out, int out_size, void* d_ws, size_t ws_size,
                              hipStream_t stream) {
  const float* inp = (const float*)d_in[0];
  const float* T   = (const float*)d_in[1];
  float* out = (float*)d_out;
  char* ws = (char*)d_ws;

  size_t off = 0;
  float*   part = (float*)(ws + off);  off += (size_t)NTn * Bn * Cn * 16 * sizeof(float);   // 36 KB
  __half2* Fxh = (__half2*)(ws + off); off += (size_t)Bn * Cn * KF * Hn * sizeof(__half2);  // 8.5 MB
  float2*  G   = (float2*)(ws + off);  off += (size_t)NTn * Bn * Hn * KGP * sizeof(float2); // 10.0 MB
  __half2* Yh  = (__half2*)(ws + off); off += (size_t)NTn * Bn * Cn * KF * Hn * sizeof(__half2); // 76 MB
  (void)off; (void)ws_size; (void)in_sizes; (void)n_in; (void)out_size;

  k_yrow<<<NTn * Bn * 64, 256, 0, stream>>>(inp, T, Yh, part);
  k_colfft_fx<<<Bn * Cn * KF / 4 / 4, 256, 0, stream>>>(Yh, Fxh);   // 516 blocks
  k_ycol<<<NTn * Bn * 33, 256, 0, stream>>>(Yh, Fxh, part, G);
  k_irow<<<Bn * Hn, 320, 0, stream>>>(G, out);
}